// Round 7
// baseline (1956.225 us; speedup 1.0000x reference)
//
#include <hip/hip_runtime.h>
#include <stdint.h>

// IndexFlatIP top-k: sims = Q[512,512] @ X[262144,512]^T, per-row top-10
// indices (desc, ties -> lower index). Output int32 [512,10].
//
// Round 7:
//  qprep: Q fp32 -> f16 RTZ granules in p1's A-tile order (512 KB).
//  xprep: X fp32 -> f16 RTZ, natural row-major granules (268 MB in d_ws).
//  p1   : pure-glds f16 MFMA GEMM. BM=128 BN=128 BK=32, 4 waves (2Mx2N,
//         wave tile 64x64), 4-deep LDS buffers, counted s_waitcnt vmcnt(8)
//         + raw s_barrier (loads stay in flight across barriers), 2 blocks/CU.
//         Fused per-row top-6 per 1024-col chunk (all-thread split scan +
//         shfl merge). p2: pivot-filter + exact fp32 rescore (verified).
#define B_Q   512
#define N_IDX 262144
#define D_DIM 512
#define TOPK  10
#define CAND  6

constexpr int CHUNKS = 256;          // candidate chunks (1024 cols each)
constexpr int NR = N_IDX / CHUNKS;   // 1024
constexpr int BM = 128, BN = 128, BK = 32;
constexpr int ITERS = (NR / BN) * (D_DIM / BK);   // 8 nt * 16 kt = 128
constexpr int NCAND = CHUNKS * CAND; // 1536
constexpr int CS_STRIDE = 17;        // Cs row stride (f32)

typedef _Float16 half8 __attribute__((ext_vector_type(8)));
typedef float    f32x4 __attribute__((ext_vector_type(4)));

__device__ __forceinline__ unsigned int pk16(float a, float b)
{
    return __builtin_bit_cast(unsigned int, __builtin_amdgcn_cvt_pkrtz(a, b));
}

__device__ __forceinline__ void glds16(const void* g, char* lds)
{
    __builtin_amdgcn_global_load_lds(
        (const __attribute__((address_space(1))) void*)g,
        (__attribute__((address_space(3))) void*)lds, 16, 0, 0);
}

// ------------------------------------------------------------------ qprep --
// Q fp32 -> f16 RTZ in A-tile granule order: tile (qt 0..3, kt 0..15) of
// 512 granules; granule = slot*128 + row (slot = k-octet 0..3, row 0..127).
__global__ __launch_bounds__(256)
void qprep(const float* __restrict__ Q, uint4* __restrict__ Qsw4)
{
    const int n = blockIdx.x * 256 + threadIdx.x;   // 32768 source granules
    const float4 p0 = reinterpret_cast<const float4*>(Q)[n * 2];
    const float4 p1 = reinterpret_cast<const float4*>(Q)[n * 2 + 1];
    uint4 u;
    u.x = pk16(p0.x, p0.y);
    u.y = pk16(p0.z, p0.w);
    u.z = pk16(p1.x, p1.y);
    u.w = pk16(p1.z, p1.w);
    const int row_g = n >> 6, oct = n & 63;         // global row, k-octet
    const int qt = row_g >> 7, row = row_g & 127;
    const int kt = oct >> 2, slot = oct & 3;
    Qsw4[(qt * 16 + kt) * 512 + slot * 128 + row] = u;
}

// ------------------------------------------------------------------ xprep --
// X fp32 -> f16 RTZ, natural layout: Xh4[n] = pack(X[n*8 .. n*8+7]).
__global__ __launch_bounds__(256)
void xprep(const float* __restrict__ X, uint4* __restrict__ Xh4)
{
    const int n = blockIdx.x * 256 + threadIdx.x;   // 16,777,216 granules
    const float4 p0 = reinterpret_cast<const float4*>(X)[(size_t)n * 2];
    const float4 p1 = reinterpret_cast<const float4*>(X)[(size_t)n * 2 + 1];
    uint4 u;
    u.x = pk16(p0.x, p0.y);
    u.y = pk16(p0.z, p0.w);
    u.z = pk16(p1.x, p1.y);
    u.w = pk16(p1.z, p1.w);
    Xh4[n] = u;
}

// --------------------------------------------------------------------- p1 --
// Grid 1024 (chunk = bx>>2, qt = bx&3), block 256 = 4 waves (wm=w>>1, wn=w&1).
// LDS 74240: A bufs 4x8K @0, B bufs 4x8K @32768, Cs 128x17 f32 @65536.
// Per step per wave: 2 A-glds + 2 B-glds, 8 ds_read_b128, 16 MFMA.
__global__ __launch_bounds__(256, 2)
void faiss_p1(const uint4* __restrict__ Qsw4, const uint4* __restrict__ Xh4,
              float* __restrict__ cand_v, int* __restrict__ cand_i)
{
    __shared__ __align__(16) char smem[74240];
    float* Cs = (float*)(smem + 65536);

    const int tid  = threadIdx.x;
    const int lane = tid & 63;
    const int w    = tid >> 6;      // 0..3 (also the B k-octet this wave stages)
    const int wm   = w >> 1;        // M half
    const int wn   = w & 1;         // N half
    const int chunk = blockIdx.x >> 2;
    const int qt    = blockIdx.x & 3;

    // A staging: wave w stages granules w*128 + i*64 + lane of tile (qt,kt).
    const uint4* aSrc0 = Qsw4 + qt * (16 * 512) + w * 128 + lane;
    const uint4* aSrc1 = aSrc0 + 64;
    const int dDst0 = (w * 128) * 16;        // wave-uniform LDS byte offset
    const int dDst1 = dDst0 + 1024;

    // B staging: wave w stages k-octet ks=w, cols i*64+lane of the nt-tile.
    // Source: Xh4[(chunk*1024 + nt*128 + col)*64 + kt*4 + w].
    const uint4* bSrc0 = Xh4 + (size_t)(chunk * NR + lane) * 64 + w;
    const uint4* bSrc1 = Xh4 + (size_t)(chunk * NR + 64 + lane) * 64 + w;

    // fragment byte offsets within an 8K buffer (granule = koct*128 + idx)
    int a_off[4], b_off[4];
#pragma unroll
    for (int i = 0; i < 4; ++i) {
        a_off[i] = ((lane >> 4) * 128 + wm * 64 + i * 16 + (lane & 15)) * 16;
        b_off[i] = ((lane >> 4) * 128 + wn * 64 + i * 16 + (lane & 15)) * 16;
    }

    float topv[CAND]; int topi[CAND];
#pragma unroll
    for (int j = 0; j < CAND; ++j) { topv[j] = -3.0e38f; topi[j] = 0; }

    f32x4 acc[4][4];
#pragma unroll
    for (int mi = 0; mi < 4; ++mi)
#pragma unroll
        for (int ni = 0; ni < 4; ++ni) acc[mi][ni] = (f32x4)0.0f;

    auto issue = [&](int s, int buf) {
        const int kt = s & 15, nt = s >> 4;
        const int    offA = kt * 512;                       // uint4 units
        const size_t offB = (size_t)nt * 8192 + kt * 4;     // 128 rows * 64
        char* ab = smem + buf * 8192;
        char* bb = smem + 32768 + buf * 8192;
        glds16(aSrc0 + offA, ab + dDst0);
        glds16(aSrc1 + offA, ab + dDst1);
        glds16(bSrc0 + offB, bb + dDst0);
        glds16(bSrc1 + offB, bb + dDst1);
    };
    auto compute = [&](int buf) {
        const char* ab = smem + buf * 8192;
        const char* bb = smem + 32768 + buf * 8192;
        half8 af[4], bf[4];
#pragma unroll
        for (int mi = 0; mi < 4; ++mi)
            af[mi] = *reinterpret_cast<const half8*>(ab + a_off[mi]);
#pragma unroll
        for (int ni = 0; ni < 4; ++ni)
            bf[ni] = *reinterpret_cast<const half8*>(bb + b_off[ni]);
#pragma unroll
        for (int mi = 0; mi < 4; ++mi)
#pragma unroll
            for (int ni = 0; ni < 4; ++ni)
                acc[mi][ni] = __builtin_amdgcn_mfma_f32_16x16x32_f16(
                    af[mi], bf[ni], acc[mi][ni], 0, 0, 0);
    };
    auto epilogue = [&](int nt) {
        const int col0g = chunk * NR + nt * BN;
#pragma unroll
        for (int s = 0; s < 8; ++s) {
            if (wn == (s >> 2)) {
                const int ni = s & 3;
#pragma unroll
                for (int mi = 0; mi < 4; ++mi)
#pragma unroll
                    for (int r = 0; r < 4; ++r) {
                        const int row = wm * 64 + mi * 16 + (lane >> 4) * 4 + r;
                        Cs[row * CS_STRIDE + (lane & 15)] = acc[mi][ni][r];
                    }
            }
            asm volatile("s_waitcnt lgkmcnt(0)" ::: "memory");
            __builtin_amdgcn_s_barrier();
            {
                const int row = tid >> 1, hf = tid & 1;
                const int base = col0g + s * 16 + hf * 8;
                for (int c = 0; c < 8; ++c) {
                    const float v = Cs[row * CS_STRIDE + hf * 8 + c];
                    const int id = base + c;
                    if (v > topv[CAND - 1] ||
                        (v == topv[CAND - 1] && id < topi[CAND - 1])) {
                        topv[CAND - 1] = v; topi[CAND - 1] = id;
#pragma unroll
                        for (int t = CAND - 1; t > 0; --t) {
                            const bool gt = topv[t] > topv[t - 1] ||
                                (topv[t] == topv[t - 1] && topi[t] < topi[t - 1]);
                            if (gt) {
                                const float tv = topv[t]; topv[t] = topv[t - 1]; topv[t - 1] = tv;
                                const int   ti = topi[t]; topi[t] = topi[t - 1]; topi[t - 1] = ti;
                            }
                        }
                    }
                }
            }
            asm volatile("s_waitcnt lgkmcnt(0)" ::: "memory");
            __builtin_amdgcn_s_barrier();
        }
#pragma unroll
        for (int mi = 0; mi < 4; ++mi)
#pragma unroll
            for (int ni = 0; ni < 4; ++ni) acc[mi][ni] = (f32x4)0.0f;
    };

    // prologue: 3 steps in flight (12 glds); drain step 0's 4, keep 8.
    issue(0, 0); issue(1, 1); issue(2, 2);
    asm volatile("s_waitcnt vmcnt(8)" ::: "memory");
    __builtin_amdgcn_s_barrier();

    for (int j = 0; j < ITERS - 4; j += 4) {
#pragma unroll
        for (int u = 0; u < 4; ++u) {
            const int jj = j + u;
            issue(jj + 3, (u + 3) & 3);
            compute(u);
            asm volatile("s_waitcnt vmcnt(8) lgkmcnt(0)" ::: "memory");
            __builtin_amdgcn_s_barrier();
            if ((jj & 15) == 15) epilogue(jj >> 4);
        }
    }
    // tail: jj = 124..127
    issue(127, 3);
    compute(0);
    asm volatile("s_waitcnt vmcnt(8) lgkmcnt(0)" ::: "memory");
    __builtin_amdgcn_s_barrier();
    compute(1);
    asm volatile("s_waitcnt vmcnt(4) lgkmcnt(0)" ::: "memory");
    __builtin_amdgcn_s_barrier();
    compute(2);
    asm volatile("s_waitcnt vmcnt(0) lgkmcnt(0)" ::: "memory");
    __builtin_amdgcn_s_barrier();
    compute(3);
    epilogue(7);

    // merge the two half-row scans (adjacent lanes) and emit top-6
    float ov[CAND]; int oi[CAND];
#pragma unroll
    for (int j = 0; j < CAND; ++j) {
        ov[j] = __shfl_xor(topv[j], 1);
        oi[j] = __shfl_xor(topi[j], 1);
    }
    if ((tid & 1) == 0) {
        float mv[CAND]; int mx[CAND];
        int a = 0, b = 0;
#pragma unroll
        for (int t = 0; t < CAND; ++t) {
            const bool ta = (b >= CAND) ||
                (a < CAND && (topv[a] > ov[b] ||
                              (topv[a] == ov[b] && topi[a] < oi[b])));
            mv[t] = ta ? topv[a] : ov[b];
            mx[t] = ta ? topi[a] : oi[b];
            if (ta) ++a; else ++b;
        }
        const int rowg = qt * BM + (tid >> 1);
        const size_t base = ((size_t)rowg * CHUNKS + chunk) * CAND;
#pragma unroll
        for (int t = 0; t < CAND; ++t) {
            cand_v[base + t] = mv[t];
            cand_i[base + t] = mx[t];
        }
    }
}

// --------------------------------------------------------------------- p2 --
// One block per row. Pivot = 24th-largest chunk-head under (v desc, idx asc)
// => pool {e >= pivot} provably contains the f16-top-24 => true top-10.
// Exact fp32 rescore of the pool from original Q,X; deterministic rank.
__global__ __launch_bounds__(256)
void faiss_p2(const float* __restrict__ cand_v, const int* __restrict__ cand_i,
              const float* __restrict__ Q, const float* __restrict__ X,
              int* __restrict__ out)
{
    __shared__ float vs[NCAND];
    __shared__ int   is[NCAND];
    __shared__ float qs[D_DIM];
    __shared__ int   Sidx[NCAND];
    __shared__ float Sval[NCAND];
    __shared__ int   scount;
    __shared__ float pivV;
    __shared__ int   pivI;

    const int row = blockIdx.x, tid = threadIdx.x;

    for (int i = tid; i < NCAND; i += 256) {
        vs[i] = cand_v[(size_t)row * NCAND + i];
        is[i] = cand_i[(size_t)row * NCAND + i];
    }
    if (tid < 128)
        ((float4*)qs)[tid] = ((const float4*)(Q + (size_t)row * D_DIM))[tid];
    if (tid == 0) scount = 0;
    __syncthreads();

    // rank the 256 chunk-heads; thread with rank 23 publishes the pivot
    {
        const float h = vs[tid * CAND];
        const int  hid = is[tid * CAND];
        int r = 0;
        for (int j = 0; j < CHUNKS; ++j) {
            const float vj = vs[j * CAND];
            r += (vj > h) || (vj == h && is[j * CAND] < hid);
        }
        if (r == 23) { pivV = h; pivI = hid; }
    }
    __syncthreads();

    // filter: keep everything >= pivot under the total order
    const float pv = pivV; const int pi = pivI;
    for (int i = tid; i < NCAND; i += 256) {
        const float v = vs[i]; const int id = is[i];
        if (v > pv || (v == pv && id <= pi)) {
            const int p = atomicAdd(&scount, 1);
            Sidx[p] = id;
        }
    }
    __syncthreads();
    const int nS = scount;

    // exact fp32 rescore: one wave per candidate, deterministic reduce
    const int wv = tid >> 6, ln = tid & 63;
    for (int si = wv; si < nS; si += 4) {
        const float* xr = X + (size_t)Sidx[si] * D_DIM + ln * 8;
        const float4 xa = *(const float4*)(xr);
        const float4 xb = *(const float4*)(xr + 4);
        const float* qp = qs + ln * 8;
        float s = 0.0f;
        s = fmaf(qp[0], xa.x, s); s = fmaf(qp[1], xa.y, s);
        s = fmaf(qp[2], xa.z, s); s = fmaf(qp[3], xa.w, s);
        s = fmaf(qp[4], xb.x, s); s = fmaf(qp[5], xb.y, s);
        s = fmaf(qp[6], xb.z, s); s = fmaf(qp[7], xb.w, s);
#pragma unroll
        for (int off = 32; off > 0; off >>= 1)
            s += __shfl_down(s, off);
        if (ln == 0) Sval[si] = s;
    }
    __syncthreads();

    // final deterministic rank-select among the pool
    for (int i = tid; i < nS; i += 256) {
        const float v = Sval[i]; const int id = Sidx[i];
        int r = 0;
        for (int j = 0; j < nS; ++j) {
            const float vj = Sval[j];
            r += (vj > v) || (vj == v && Sidx[j] < id);
        }
        if (r < TOPK) out[row * TOPK + r] = id;
    }
}

// ----------------------------------------------------------------- launch --
extern "C" void kernel_launch(void* const* d_in, const int* in_sizes, int n_in,
                              void* d_out, int out_size, void* d_ws, size_t ws_size,
                              hipStream_t stream)
{
    (void)in_sizes; (void)n_in; (void)out_size; (void)ws_size;
    const float* Q = (const float*)d_in[0];
    const float* X = (const float*)d_in[1];
    int* out = (int*)d_out;

    char* ws = (char*)d_ws;
    float* cand_v = (float*)ws;                              // 3.15 MB
    int*   cand_i = (int*)(ws + (size_t)B_Q * NCAND * 4);    // 3.15 MB
    uint4* Qsw4   = (uint4*)(ws + (size_t)B_Q * NCAND * 8);  // 512 KB
    uint4* Xh4    = (uint4*)(ws + (size_t)B_Q * NCAND * 8 + 524288);  // 268 MB

    qprep<<<dim3(128),   dim3(256), 0, stream>>>(Q, Qsw4);
    xprep<<<dim3(65536), dim3(256), 0, stream>>>(X, Xh4);
    faiss_p1<<<dim3(1024), dim3(256), 0, stream>>>(Qsw4, Xh4, cand_v, cand_i);
    faiss_p2<<<dim3(B_Q),  dim3(256), 0, stream>>>(cand_v, cand_i, Q, X, out);
}